// Round 1
// baseline (183.259 us; speedup 1.0000x reference)
//
#include <hip/hip_runtime.h>
#include <hip/hip_bf16.h>

#define NBAGS 16384
#define OUT_STRIDE 288

struct ScanPtrs {
    const int* lens[4];
    int* starts[4];
};

// One block per table: exclusive prefix-sum of lens[16384] -> starts[16384].
__global__ void __launch_bounds__(256) scan_kernel(ScanPtrs p) {
    const int t = blockIdx.x;
    const int* __restrict__ lens = p.lens[t];
    int* __restrict__ starts = p.starts[t];
    __shared__ int psum[256];
    const int tid = threadIdx.x;
    constexpr int CHUNK = NBAGS / 256;  // 64
    const int base = tid * CHUNK;

    int s = 0;
    for (int k = 0; k < CHUNK; ++k) s += lens[base + k];
    psum[tid] = s;
    __syncthreads();

    // Hillis-Steele inclusive scan over 256 partials
    for (int off = 1; off < 256; off <<= 1) {
        int v = psum[tid];
        int add = (tid >= off) ? psum[tid - off] : 0;
        __syncthreads();
        psum[tid] = v + add;
        __syncthreads();
    }

    int run = (tid == 0) ? 0 : psum[tid - 1];
    for (int k = 0; k < CHUNK; ++k) {
        starts[base + k] = run;
        run += lens[base + k];
    }
}

template <int VPT>
__device__ inline void addrow(float (&a)[VPT], const float* __restrict__ p) {
    if constexpr (VPT == 1) {
        a[0] += *p;
    } else {
        const float2 v = *reinterpret_cast<const float2*>(p);
        a[0] += v.x;
        a[1] += v.y;
    }
}

// D/VPT threads cooperate on one bag; row loads are contiguous per group.
template <int D, int VPT>
__global__ void __launch_bounds__(256) pool_kernel(
    const float* __restrict__ W, const int* __restrict__ ids,
    const int* __restrict__ starts, const int* __restrict__ lens,
    float* __restrict__ out, int col_off)
{
    constexpr int TPB = D / VPT;  // threads per bag
    const int gid = blockIdx.x * 256 + threadIdx.x;
    const int bag = gid / TPB;
    const int lane = gid % TPB;
    if (bag >= NBAGS) return;

    const int s = starts[bag];
    const int n = lens[bag];
    const float* __restrict__ Wl = W + (size_t)(lane * VPT);

    float a0[VPT], a1[VPT], a2[VPT], a3[VPT];
#pragma unroll
    for (int v = 0; v < VPT; ++v) { a0[v] = 0.f; a1[v] = 0.f; a2[v] = 0.f; a3[v] = 0.f; }

    int j = 0;
    // 4-way unroll: 4 independent id->row load chains in flight
    for (; j + 4 <= n; j += 4) {
        const int i0 = ids[s + j + 0];
        const int i1 = ids[s + j + 1];
        const int i2 = ids[s + j + 2];
        const int i3 = ids[s + j + 3];
        addrow<VPT>(a0, Wl + (size_t)i0 * D);
        addrow<VPT>(a1, Wl + (size_t)i1 * D);
        addrow<VPT>(a2, Wl + (size_t)i2 * D);
        addrow<VPT>(a3, Wl + (size_t)i3 * D);
    }
    for (; j < n; ++j) {
        const int i0 = ids[s + j];
        addrow<VPT>(a0, Wl + (size_t)i0 * D);
    }

    float* __restrict__ o = out + (size_t)bag * OUT_STRIDE + col_off + lane * VPT;
#pragma unroll
    for (int v = 0; v < VPT; ++v) o[v] = a0[v] + a1[v] + a2[v] + a3[v];
}

extern "C" void kernel_launch(void* const* d_in, const int* in_sizes, int n_in,
                              void* d_out, int out_size, void* d_ws, size_t ws_size,
                              hipStream_t stream) {
    const float* W0   = (const float*)d_in[0];
    const int*   ids0 = (const int*)d_in[1];
    const int*   len0 = (const int*)d_in[2];
    const float* W1   = (const float*)d_in[3];
    const int*   ids1 = (const int*)d_in[4];
    const int*   len1 = (const int*)d_in[5];
    const float* W2   = (const float*)d_in[6];
    const int*   ids2 = (const int*)d_in[7];
    const int*   len2 = (const int*)d_in[8];
    const float* W3   = (const float*)d_in[9];
    const int*   ids3 = (const int*)d_in[10];
    const int*   len3 = (const int*)d_in[11];
    float* out = (float*)d_out;

    int* starts = (int*)d_ws;  // 4 * 16384 * 4B = 256 KB

    ScanPtrs sp;
    sp.lens[0] = len0; sp.lens[1] = len1; sp.lens[2] = len2; sp.lens[3] = len3;
    for (int t = 0; t < 4; ++t) sp.starts[t] = starts + t * NBAGS;

    scan_kernel<<<4, 256, 0, stream>>>(sp);

    // table 0: D=64, 64 threads/bag -> 4 bags/block
    pool_kernel<64, 1><<<NBAGS * 64 / 256, 256, 0, stream>>>(
        W0, ids0, starts + 0 * NBAGS, len0, out, 0);
    // table 1: D=128, float2, 64 threads/bag
    pool_kernel<128, 2><<<NBAGS * 64 / 256, 256, 0, stream>>>(
        W1, ids1, starts + 1 * NBAGS, len1, out, 64);
    // table 2: D=32, 32 threads/bag -> 8 bags/block
    pool_kernel<32, 1><<<NBAGS * 32 / 256, 256, 0, stream>>>(
        W2, ids2, starts + 2 * NBAGS, len2, out, 192);
    // table 3: D=64
    pool_kernel<64, 1><<<NBAGS * 64 / 256, 256, 0, stream>>>(
        W3, ids3, starts + 3 * NBAGS, len3, out, 224);
}

// Round 2
// 146.286 us; speedup vs baseline: 1.2527x; 1.2527x over previous
//
#include <hip/hip_runtime.h>
#include <hip/hip_bf16.h>

#define NBAGS 16384
#define OUT_STRIDE 288

struct Ptrs {
    const float* W[4];
    const int* ids[4];
    const int* lens[4];
    int* starts[4];
    float* out;
};

// Brute-force chunked exclusive scan: grid = 4 tables x 256 chunks.
// Block (t, c) computes starts for bags [c*64, c*64+64) by redundantly
// summing lens[0 .. c*64) (L2-resident after first touch) + wave-scan of 64.
__global__ void __launch_bounds__(256) scan_kernel(Ptrs p) {
    const int t = blockIdx.x >> 8;          // /256
    const int c = blockIdx.x & 255;
    const int* __restrict__ lens = p.lens[t];
    int* __restrict__ starts = p.starts[t];
    const int tid = threadIdx.x;
    const int P = c * 64;  // bags before this chunk

    __shared__ int red[256];
    int s = 0;
    for (int k = tid; k < P; k += 256) s += lens[k];
    red[tid] = s;
    __syncthreads();
    for (int off = 128; off > 0; off >>= 1) {
        if (tid < off) red[tid] += red[tid + off];
        __syncthreads();
    }
    const int prefix = red[0];

    if (tid < 64) {
        const int v = lens[P + tid];
        int inc = v;
#pragma unroll
        for (int off = 1; off < 64; off <<= 1) {
            int u = __shfl_up(inc, off, 64);
            if (tid >= off) inc += u;
        }
        starts[P + tid] = prefix + inc - v;
    }
}

template <int D, int UNROLL>
__device__ __forceinline__ void pool_bags(
    const float* __restrict__ W, const int* __restrict__ ids,
    const int* __restrict__ starts, const int* __restrict__ lens,
    float* __restrict__ out, int col_off, int blk)
{
    constexpr int TPB = D / 4;        // threads per bag (float4 lanes)
    constexpr int BAGS = 256 / TPB;   // bags per block
    constexpr int RS = D / 4;         // row stride in float4

    const int bag = blk * BAGS + threadIdx.x / TPB;
    const int lane = threadIdx.x % TPB;
    const int s = starts[bag];
    const int n = lens[bag];
    const float4* __restrict__ Wl = reinterpret_cast<const float4*>(W) + lane;

    float4 acc[UNROLL];
#pragma unroll
    for (int u = 0; u < UNROLL; ++u) acc[u] = make_float4(0.f, 0.f, 0.f, 0.f);

    int j = 0;
    for (; j + UNROLL <= n; j += UNROLL) {
        int idx[UNROLL];
#pragma unroll
        for (int u = 0; u < UNROLL; ++u) idx[u] = ids[s + j + u];
#pragma unroll
        for (int u = 0; u < UNROLL; ++u) {
            const float4 v = Wl[(size_t)idx[u] * RS];
            acc[u].x += v.x; acc[u].y += v.y; acc[u].z += v.z; acc[u].w += v.w;
        }
    }
    for (; j < n; ++j) {
        const float4 v = Wl[(size_t)ids[s + j] * RS];
        acc[0].x += v.x; acc[0].y += v.y; acc[0].z += v.z; acc[0].w += v.w;
    }

#pragma unroll
    for (int u = 1; u < UNROLL; ++u) {
        acc[0].x += acc[u].x; acc[0].y += acc[u].y;
        acc[0].z += acc[u].z; acc[0].w += acc[u].w;
    }

    float4* __restrict__ o = reinterpret_cast<float4*>(
        out + (size_t)bag * OUT_STRIDE + col_off) + lane;
    *o = acc[0];
}

// Block ranges (256 thr): T0 D=64 -> 1024 blocks, T1 D=128 -> 2048,
// T2 D=32 -> 512, T3 D=64 -> 1024.  Total 4608.
#define B0 1024
#define B1 3072
#define B2 3584
#define B3 4608

__global__ void __launch_bounds__(256) pool_fused(Ptrs p) {
    const int b = blockIdx.x;
    if (b < B0) {
        pool_bags<64, 8>(p.W[0], p.ids[0], p.starts[0], p.lens[0], p.out, 0, b);
    } else if (b < B1) {
        pool_bags<128, 8>(p.W[1], p.ids[1], p.starts[1], p.lens[1], p.out, 64, b - B0);
    } else if (b < B2) {
        pool_bags<32, 8>(p.W[2], p.ids[2], p.starts[2], p.lens[2], p.out, 192, b - B1);
    } else {
        pool_bags<64, 8>(p.W[3], p.ids[3], p.starts[3], p.lens[3], p.out, 224, b - B2);
    }
}

extern "C" void kernel_launch(void* const* d_in, const int* in_sizes, int n_in,
                              void* d_out, int out_size, void* d_ws, size_t ws_size,
                              hipStream_t stream) {
    Ptrs p;
    for (int t = 0; t < 4; ++t) {
        p.W[t]    = (const float*)d_in[3 * t + 0];
        p.ids[t]  = (const int*)d_in[3 * t + 1];
        p.lens[t] = (const int*)d_in[3 * t + 2];
        p.starts[t] = (int*)d_ws + t * NBAGS;
    }
    p.out = (float*)d_out;

    scan_kernel<<<1024, 256, 0, stream>>>(p);
    pool_fused<<<B3, 256, 0, stream>>>(p);
}

// Round 3
// 137.794 us; speedup vs baseline: 1.3300x; 1.0616x over previous
//
#include <hip/hip_runtime.h>
#include <hip/hip_bf16.h>

#define NBAGS 16384
#define OUT_STRIDE 288

struct Ptrs {
    const float* W[4];
    const int* ids[4];
    const int* lens[4];
    int* starts[4];
    float* out;
};

// Brute-force chunked exclusive scan: grid = 4 tables x 256 chunks.
__global__ void __launch_bounds__(256) scan_kernel(Ptrs p) {
    const int t = blockIdx.x >> 8;
    const int c = blockIdx.x & 255;
    const int* __restrict__ lens = p.lens[t];
    int* __restrict__ starts = p.starts[t];
    const int tid = threadIdx.x;
    const int P = c * 64;

    __shared__ int red[256];
    int s = 0;
    for (int k = tid; k < P; k += 256) s += lens[k];
    red[tid] = s;
    __syncthreads();
    for (int off = 128; off > 0; off >>= 1) {
        if (tid < off) red[tid] += red[tid + off];
        __syncthreads();
    }
    const int prefix = red[0];

    if (tid < 64) {
        const int v = lens[P + tid];
        int inc = v;
#pragma unroll
        for (int off = 1; off < 64; off <<= 1) {
            int u = __shfl_up(inc, off, 64);
            if (tid >= off) inc += u;
        }
        starts[P + tid] = prefix + inc - v;
    }
}

// One unit = 8 bags, 256 threads. Each bag is worked by G groups of TPB=D/4
// lanes (float4 per lane); strided row split across groups; LDS reduce.
template <int D, int G, int UNROLL>
__device__ __forceinline__ void pool_unit(
    const float* __restrict__ W, const int* __restrict__ ids,
    const int* __restrict__ starts, const int* __restrict__ lens,
    float* __restrict__ out, int col_off, int chunk, float4* sm)
{
    constexpr int TPB = D / 4;             // lanes per group
    constexpr int SLOTS = 256 / (TPB * G); // bags per block (= 8 for all tables)
    const int tid = threadIdx.x;
    const int slot = tid / (TPB * G);
    const int g = (tid / TPB) % G;
    const int lane = tid % TPB;
    const int bag = chunk * SLOTS + slot;
    const int s = starts[bag];
    const int n = lens[bag];
    const float4* __restrict__ Wl = reinterpret_cast<const float4*>(W) + lane;

    float4 acc[UNROLL];
#pragma unroll
    for (int u = 0; u < UNROLL; ++u) acc[u] = make_float4(0.f, 0.f, 0.f, 0.f);

    // group g owns rows j = g, g+G, g+2G, ...
    int j = g;
    for (; j + (UNROLL - 1) * G < n; j += UNROLL * G) {
        int idx[UNROLL];
#pragma unroll
        for (int u = 0; u < UNROLL; ++u) idx[u] = ids[s + j + u * G];
#pragma unroll
        for (int u = 0; u < UNROLL; ++u) {
            const float4 v = Wl[(size_t)idx[u] * TPB];
            acc[u].x += v.x; acc[u].y += v.y; acc[u].z += v.z; acc[u].w += v.w;
        }
    }
    // masked epilogue: keep UNROLL loads in flight for the remainder too
    if (j < n) {
        int idx[UNROLL];
        bool ok[UNROLL];
#pragma unroll
        for (int u = 0; u < UNROLL; ++u) {
            const int jj = j + u * G;
            ok[u] = (jj < n);
            idx[u] = ids[s + (ok[u] ? jj : (n - 1))];
        }
#pragma unroll
        for (int u = 0; u < UNROLL; ++u) {
            const float4 v = Wl[(size_t)idx[u] * TPB];
            if (ok[u]) {
                acc[u].x += v.x; acc[u].y += v.y; acc[u].z += v.z; acc[u].w += v.w;
            }
        }
    }

#pragma unroll
    for (int u = 1; u < UNROLL; ++u) {
        acc[0].x += acc[u].x; acc[0].y += acc[u].y;
        acc[0].z += acc[u].z; acc[0].w += acc[u].w;
    }

    if constexpr (G == 1) {
        float4* o = reinterpret_cast<float4*>(out + (size_t)bag * OUT_STRIDE + col_off) + lane;
        *o = acc[0];
    } else {
        sm[tid] = acc[0];
        __syncthreads();
        if (g == 0) {
#pragma unroll
            for (int h = 1; h < G; ++h) {
                const float4 v = sm[tid + h * TPB];
                acc[0].x += v.x; acc[0].y += v.y; acc[0].z += v.z; acc[0].w += v.w;
            }
            float4* o = reinterpret_cast<float4*>(out + (size_t)bag * OUT_STRIDE + col_off) + lane;
            *o = acc[0];
        }
    }
}

// grid = 8192: unit u -> table u&3, chunk u>>2. 8 bags/unit everywhere ->
// uniform ~82-102 KB work per block, all tables concurrently resident.
__global__ void __launch_bounds__(256) pool_fused(Ptrs p) {
    __shared__ float4 sm[256];
    const int u = blockIdx.x;
    const int chunk = u >> 2;
    switch (u & 3) {
    case 0: pool_unit<64, 2, 8>(p.W[0], p.ids[0], p.starts[0], p.lens[0], p.out, 0,   chunk, sm); break;
    case 1: pool_unit<128, 1, 8>(p.W[1], p.ids[1], p.starts[1], p.lens[1], p.out, 64,  chunk, sm); break;
    case 2: pool_unit<32, 4, 8>(p.W[2], p.ids[2], p.starts[2], p.lens[2], p.out, 192, chunk, sm); break;
    default: pool_unit<64, 2, 8>(p.W[3], p.ids[3], p.starts[3], p.lens[3], p.out, 224, chunk, sm); break;
    }
}

extern "C" void kernel_launch(void* const* d_in, const int* in_sizes, int n_in,
                              void* d_out, int out_size, void* d_ws, size_t ws_size,
                              hipStream_t stream) {
    Ptrs p;
    for (int t = 0; t < 4; ++t) {
        p.W[t]    = (const float*)d_in[3 * t + 0];
        p.ids[t]  = (const int*)d_in[3 * t + 1];
        p.lens[t] = (const int*)d_in[3 * t + 2];
        p.starts[t] = (int*)d_ws + t * NBAGS;
    }
    p.out = (float*)d_out;

    scan_kernel<<<1024, 256, 0, stream>>>(p);
    pool_fused<<<NBAGS / 8 * 4, 256, 0, stream>>>(p);
}

// Round 4
// 136.382 us; speedup vs baseline: 1.3437x; 1.0104x over previous
//
#include <hip/hip_runtime.h>
#include <hip/hip_bf16.h>

#define NBAGS 16384
#define OUT_STRIDE 288

struct Ptrs {
    const float* W[4];
    const int* ids[4];
    const int* lens[4];
    int* starts[4];
    float* out;
};

// Brute-force chunked exclusive scan: grid = 4 tables x 256 chunks.
__global__ void __launch_bounds__(256) scan_kernel(Ptrs p) {
    const int t = blockIdx.x >> 8;
    const int c = blockIdx.x & 255;
    const int* __restrict__ lens = p.lens[t];
    int* __restrict__ starts = p.starts[t];
    const int tid = threadIdx.x;
    const int P = c * 64;

    __shared__ int red[256];
    int s = 0;
    for (int k = tid; k < P; k += 256) s += lens[k];
    red[tid] = s;
    __syncthreads();
    for (int off = 128; off > 0; off >>= 1) {
        if (tid < off) red[tid] += red[tid + off];
        __syncthreads();
    }
    const int prefix = red[0];

    if (tid < 64) {
        const int v = lens[P + tid];
        int inc = v;
#pragma unroll
        for (int off = 1; off < 64; off <<= 1) {
            int u = __shfl_up(inc, off, 64);
            if (tid >= off) inc += u;
        }
        starts[P + tid] = prefix + inc - v;
    }
}

// One unit = 8 bags, 256 threads; G groups of TPB=D/4 lanes per bag.
// Software-pipelined: double-buffered id batches (static names), explicit
// row buffers, uniform base + 32-bit voffset addressing -> 8 gathers in
// flight per group at all times (incl. masked tail batches).
template <int D, int G, int U>
__device__ __forceinline__ void pool_unit(
    const float* __restrict__ W, const int* __restrict__ ids,
    const int* __restrict__ starts, const int* __restrict__ lens,
    float* __restrict__ out, int col_off, int chunk, float4* sm)
{
    constexpr int TPB = D / 4;             // lanes per group
    constexpr int SLOTS = 256 / (TPB * G); // bags per block (8 everywhere)
    constexpr unsigned RB = (unsigned)(D * 4);  // row bytes
    const int tid = threadIdx.x;
    const int slot = tid / (TPB * G);
    const int g = (tid / TPB) % G;
    const int lane = tid % TPB;
    const int bag = chunk * SLOTS + slot;
    const int s = starts[bag];
    const int n = lens[bag];
    const char* __restrict__ Wb = reinterpret_cast<const char*>(W);
    const unsigned lane16 = (unsigned)(lane * 16);

    float4 acc[U];
#pragma unroll
    for (int u = 0; u < U; ++u) acc[u] = make_float4(0.f, 0.f, 0.f, 0.f);

    // batch b covers rows j = g + (b*U + u)*G for u in [0,U)
    int j0 = g;
    int idxA[U];
#pragma unroll
    for (int u = 0; u < U; ++u) {
        const int jj = j0 + u * G;
        idxA[u] = (jj < n) ? ids[s + jj] : -1;
    }

    while (true) {
        // issue U gathers for current batch (always load; mask the add)
        float4 r[U];
#pragma unroll
        for (int u = 0; u < U; ++u) {
            const int id = idxA[u];
            const unsigned off = (unsigned)(id < 0 ? 0 : id) * RB + lane16;
            r[u] = *reinterpret_cast<const float4*>(Wb + off);
        }
        // prefetch next batch ids while gathers are in flight
        const int j1 = j0 + U * G;
        int idxB[U];
#pragma unroll
        for (int u = 0; u < U; ++u) {
            const int jj = j1 + u * G;
            idxB[u] = (jj < n) ? ids[s + jj] : -1;
        }
        // accumulate (masked via multiplier so tails stay branch-free)
#pragma unroll
        for (int u = 0; u < U; ++u) {
            const float m = (idxA[u] >= 0) ? 1.f : 0.f;
            acc[u].x = fmaf(m, r[u].x, acc[u].x);
            acc[u].y = fmaf(m, r[u].y, acc[u].y);
            acc[u].z = fmaf(m, r[u].z, acc[u].z);
            acc[u].w = fmaf(m, r[u].w, acc[u].w);
        }
        j0 = j1;
        if (j0 >= n) break;
#pragma unroll
        for (int u = 0; u < U; ++u) idxA[u] = idxB[u];
    }

#pragma unroll
    for (int u = 1; u < U; ++u) {
        acc[0].x += acc[u].x; acc[0].y += acc[u].y;
        acc[0].z += acc[u].z; acc[0].w += acc[u].w;
    }

    if constexpr (G == 1) {
        float4* o = reinterpret_cast<float4*>(out + (size_t)bag * OUT_STRIDE + col_off) + lane;
        *o = acc[0];
    } else {
        sm[tid] = acc[0];
        __syncthreads();
        if (g == 0) {
#pragma unroll
            for (int h = 1; h < G; ++h) {
                const float4 v = sm[tid + h * TPB];
                acc[0].x += v.x; acc[0].y += v.y; acc[0].z += v.z; acc[0].w += v.w;
            }
            float4* o = reinterpret_cast<float4*>(out + (size_t)bag * OUT_STRIDE + col_off) + lane;
            *o = acc[0];
        }
    }
}

// grid = 8192: unit u -> table u&3, chunk u>>2; uniform work per block.
__global__ void __launch_bounds__(256) pool_fused(Ptrs p) {
    __shared__ float4 sm[256];
    const int u = blockIdx.x;
    const int chunk = u >> 2;
    switch (u & 3) {
    case 0: pool_unit<64, 2, 8>(p.W[0], p.ids[0], p.starts[0], p.lens[0], p.out, 0,   chunk, sm); break;
    case 1: pool_unit<128, 1, 8>(p.W[1], p.ids[1], p.starts[1], p.lens[1], p.out, 64,  chunk, sm); break;
    case 2: pool_unit<32, 4, 8>(p.W[2], p.ids[2], p.starts[2], p.lens[2], p.out, 192, chunk, sm); break;
    default: pool_unit<64, 2, 8>(p.W[3], p.ids[3], p.starts[3], p.lens[3], p.out, 224, chunk, sm); break;
    }
}

extern "C" void kernel_launch(void* const* d_in, const int* in_sizes, int n_in,
                              void* d_out, int out_size, void* d_ws, size_t ws_size,
                              hipStream_t stream) {
    Ptrs p;
    for (int t = 0; t < 4; ++t) {
        p.W[t]    = (const float*)d_in[3 * t + 0];
        p.ids[t]  = (const int*)d_in[3 * t + 1];
        p.lens[t] = (const int*)d_in[3 * t + 2];
        p.starts[t] = (int*)d_ws + t * NBAGS;
    }
    p.out = (float*)d_out;

    scan_kernel<<<1024, 256, 0, stream>>>(p);
    pool_fused<<<NBAGS / 8 * 4, 256, 0, stream>>>(p);
}